// Round 10
// baseline (524.666 us; speedup 1.0000x reference)
//
#include <hip/hip_runtime.h>
#include <stdint.h>

#define NSCENE 16
#define NPED 32
#define HD 64
#define ED 64
#define D1 8192
#define BOTN 1024

typedef unsigned short ushort_t;
typedef __attribute__((ext_vector_type(4))) float f32x4;
typedef __attribute__((ext_vector_type(8))) __bf16 bf16x8;  // gfx950 mfma operand
typedef __attribute__((ext_vector_type(4))) unsigned int u32x4;
typedef __attribute__((ext_vector_type(2))) unsigned int u32x2;

__device__ __forceinline__ float bf2f(ushort_t u) {
  union { unsigned int i; float f; } x;
  x.i = ((unsigned int)u) << 16;
  return x.f;
}

__device__ __forceinline__ ushort_t f2bf(float f) {
  union { float f; unsigned int i; } x;
  x.f = f;
  unsigned int u = x.i + 0x7fffu + ((x.i >> 16) & 1u);
  return (ushort_t)(u >> 16);
}

// pack two f32 -> two bf16 RNE (lo in bits [15:0])
__device__ __forceinline__ unsigned int packbf(float lo, float hi) {
#if __has_builtin(__builtin_amdgcn_cvt_pk_bf16_f32)
  typedef __attribute__((ext_vector_type(2))) __bf16 bf16x2_t;
  union { bf16x2_t v; unsigned int u; } x;
  x.v = __builtin_amdgcn_cvt_pk_bf16_f32(lo, hi);
  return x.u;
#else
  return (unsigned int)f2bf(lo) | ((unsigned int)f2bf(hi) << 16);
#endif
}

// unpack u32 holding 2 bf16 -> 2 f32
__device__ __forceinline__ void unpk(unsigned int u, float& lo, float& hi) {
  union { unsigned int i; float f; } a, b;
  a.i = u << 16;
  b.i = u & 0xffff0000u;
  lo = a.f;
  hi = b.f;
}

__device__ __forceinline__ float clip1(float x) {
  return fminf(fmaxf(x, -1.f), 1.f);
}

// async global->LDS DMA, 16B/lane; LDS dest = wave-uniform base + lane*16.
__device__ __forceinline__ void async_load16(const void* g, void* l) {
  __builtin_amdgcn_global_load_lds(
      (const __attribute__((address_space(1))) unsigned int*)(unsigned long long)g,
      (__attribute__((address_space(3))) unsigned int*)(unsigned int)(unsigned long long)l,
      16, 0, 0);
}

// ---------------------------------------------------------------------------
// k_pre: preprocessing.  CHANGE vs v9: the hc buffer is written in PERMUTED
// fragment layout hcP[s][k/8][b][k%8] (b = row%32, 8 MB total) so that k_gemm
// can gather A-fragment operands COALESCED (v5's in-register gen died on the
// 16KB-stride row gather; this layout is the fix).
// ---------------------------------------------------------------------------
__global__ __launch_bounds__(256) void k_pre(
    const void* __restrict__ hv_, const void* __restrict__ end_posv,
    const void* __restrict__ W_spv, const void* __restrict__ b_spv,
    const void* __restrict__ W1v, const void* __restrict__ b1v,
    const void* __restrict__ W2v, const void* __restrict__ b2v,
    int* __restrict__ flag, float* __restrict__ epf, float* __restrict__ b2f,
    float* __restrict__ M0, float* __restrict__ M1,
    ushort_t* __restrict__ hcP, ushort_t* __restrict__ W2T) {
  __shared__ ushort_t tile[64][72];
  __shared__ int cnt[256];
  __shared__ int isbf_sh;
  const int t = threadIdx.x;
  const int bid = blockIdx.x;

  // ---- inline dtype detection ----
  {
    const ushort_t* wu = (const ushort_t*)W1v;
    unsigned int u = wu[2 * t];
    int e = (u >> 7) & 0xff;
    cnt[t] = (e >= 90 && e <= 140) ? 1 : 0;
    __syncthreads();
    for (int ofs = 128; ofs > 0; ofs >>= 1) {
      if (t < ofs) cnt[t] += cnt[t + ofs];
      __syncthreads();
    }
    if (t == 0) isbf_sh = (cnt[0] >= 128) ? 1 : 0;
    __syncthreads();
  }
  const int isbf = isbf_sh;

  if (bid < 256) {
    // ================= hc: hcP[s][k/8][b][k%8] = hbias[k] + h[row]@W1[64:] ==
    const int kb = bid & 7, jt = bid >> 3;
    const int kbase = kb * 1024 + t * 4;
    float hb0, hb1, hb2, hb3;
    if (isbf) {
      const ushort_t* b1u = (const ushort_t*)b1v;
      const ushort_t* bspu = (const ushort_t*)b_spv;
      const ushort_t* wp = (const ushort_t*)W1v + kbase;
      hb0 = bf2f(b1u[kbase]); hb1 = bf2f(b1u[kbase + 1]);
      hb2 = bf2f(b1u[kbase + 2]); hb3 = bf2f(b1u[kbase + 3]);
      for (int e = 0; e < ED; ++e) {
        float bs = bf2f(bspu[e]);
        u32x2 wv = *(const u32x2*)(wp + (size_t)e * D1);
        float w0, w1, w2, w3;
        unpk(wv.x, w0, w1); unpk(wv.y, w2, w3);
        hb0 += bs * w0; hb1 += bs * w1; hb2 += bs * w2; hb3 += bs * w3;
      }
    } else {
      const float* b1f = (const float*)b1v;
      const float* bspf = (const float*)b_spv;
      const float* wp = (const float*)W1v + kbase;
      hb0 = b1f[kbase]; hb1 = b1f[kbase + 1];
      hb2 = b1f[kbase + 2]; hb3 = b1f[kbase + 3];
      for (int e = 0; e < ED; ++e) {
        float bs = bspf[e];
        float4 w = *(const float4*)(wp + (size_t)e * D1);
        hb0 += bs * w.x; hb1 += bs * w.y; hb2 += bs * w.z; hb3 += bs * w.w;
      }
    }
    float acc[16][4];
#pragma unroll
    for (int j = 0; j < 16; ++j)
#pragma unroll
      for (int c = 0; c < 4; ++c) acc[j][c] = 0.f;
    if (isbf) {
      const ushort_t* wp = (const ushort_t*)W1v + (size_t)ED * D1 + kbase;
      const ushort_t* hp = (const ushort_t*)hv_ + jt * 16 * HD;
      for (int hh = 0; hh < HD; ++hh) {
        u32x2 wv = *(const u32x2*)(wp + (size_t)hh * D1);
        float w0, w1, w2, w3;
        unpk(wv.x, w0, w1); unpk(wv.y, w2, w3);
#pragma unroll
        for (int j = 0; j < 16; ++j) {
          float hj = bf2f(hp[j * HD + hh]);
          acc[j][0] += hj * w0;
          acc[j][1] += hj * w1;
          acc[j][2] += hj * w2;
          acc[j][3] += hj * w3;
        }
      }
    } else {
      const float* wp = (const float*)W1v + (size_t)ED * D1 + kbase;
      const float* hp = (const float*)hv_ + jt * 16 * HD;
#pragma unroll 4
      for (int hh = 0; hh < HD; ++hh) {
        float4 w = *(const float4*)(wp + (size_t)hh * D1);
#pragma unroll
        for (int j = 0; j < 16; ++j) {
          float hj = hp[j * HD + hh];
          acc[j][0] += hj * w.x;
          acc[j][1] += hj * w.y;
          acc[j][2] += hj * w.z;
          acc[j][3] += hj * w.w;
        }
      }
    }
    // permuted write: row = jt*16+j = s*32 + b; k = kc8*8 + e0 + c
    const int s2 = jt >> 1;
    const int b0 = (jt & 1) * 16;
    const int kc8 = kbase >> 3, e0 = kbase & 7;  // e0 in {0,4}
#pragma unroll
    for (int j = 0; j < 16; ++j) {
      u32x2 pk;
      pk.x = packbf(acc[j][0] + hb0, acc[j][1] + hb1);
      pk.y = packbf(acc[j][2] + hb2, acc[j][3] + hb3);
      *(u32x2*)(hcP + ((size_t)(s2 * 1024 + kc8) * 32 + b0 + j) * 8 + e0) = pk;
    }
  } else if (bid < 2304) {
    // ================= W2 transpose =================
    const int idx = bid - 256;
    const int kt = idx & 127, nt = idx >> 7;
    const int r = t >> 3, c8 = (t & 7) * 8;
#pragma unroll
    for (int i = 0; i < 2; ++i) {
      int row = i * 32 + r;
      size_t base = (size_t)(kt * 64 + row) * BOTN + nt * 64 + c8;
      if (isbf) {
        u32x4 v = *(const u32x4*)((const ushort_t*)W2v + base);
        *(u32x4*)&tile[row][c8] = v;
      } else {
        const float* src = (const float*)W2v + base;
        float4 w0 = *(const float4*)src;
        float4 w1 = *(const float4*)(src + 4);
        u32x4 pk;
        pk.x = packbf(w0.x, w0.y);
        pk.y = packbf(w0.z, w0.w);
        pk.z = packbf(w1.x, w1.y);
        pk.w = packbf(w1.z, w1.w);
        *(u32x4*)&tile[row][c8] = pk;
      }
    }
    __syncthreads();
#pragma unroll
    for (int i = 0; i < 2; ++i) {
      int nrow = i * 32 + r;
      union { ushort_t us[8]; u32x4 v; } pk;
#pragma unroll
      for (int jj = 0; jj < 8; ++jj) pk.us[jj] = tile[c8 + jj][nrow];
      *(u32x4*)(W2T + (size_t)(nt * 64 + nrow) * D1 + kt * 64 + c8) = pk.v;
    }
  } else if (bid < 2336) {
    // ================= M0/M1 fold =================
    const int k = (bid - 2304) * 256 + t;
    float m0 = 0.f, m1 = 0.f;
    if (isbf) {
      const ushort_t* Wspu = (const ushort_t*)W_spv;
      const ushort_t* W1u = (const ushort_t*)W1v;
      for (int e = 0; e < ED; ++e) {
        float w = bf2f(W1u[e * D1 + k]);
        m0 += bf2f(Wspu[e]) * w;
        m1 += bf2f(Wspu[ED + e]) * w;
      }
    } else {
      const float* Wspf = (const float*)W_spv;
      const float* W1f = (const float*)W1v;
      for (int e = 0; e < ED; ++e) {
        float w = W1f[e * D1 + k];
        m0 += Wspf[e] * w;
        m1 += Wspf[ED + e] * w;
      }
    }
    M0[k] = m0;
    M1[k] = m1;
  } else {
    // ================= epf / b2f / flag =================
    if (t == 0) *flag = isbf;
    const ushort_t* epu = (const ushort_t*)end_posv;
    const float* epff = (const float*)end_posv;
    const ushort_t* b2u = (const ushort_t*)b2v;
    const float* b2ff = (const float*)b2v;
    for (int i = t; i < 1024; i += 256) {
      epf[i] = isbf ? bf2f(epu[i]) : epff[i];
      b2f[i] = isbf ? bf2f(b2u[i]) : b2ff[i];
    }
  }
}

// ---------------------------------------------------------------------------
// k_gemm v10: v5's in-register A-gen structure + COALESCED hcP gather.
// BM=256 BN=256 BK=64, 512 thr = 8 waves as 4M x 2N (wave tile 64m x 128n).
// Grid 256 = 1 block/CU.  Only B is LDS-staged (double-buffered DMA, 64 KB,
// XOR-chunk swizzle — v5/v9-proven byte-for-byte).  A-fragments are generated
// in registers: lane (rl,q) loads hcP[chunk][bi*16+rl] (lanes 0-15 contiguous
// 256B -> coalesced; this was v5's sole failure mode) + M0/M1 chunks, then
// 2 FMA + relu + cvt_pk per element.  No A LDS traffic, no A write->read
// barrier coupling.  One __syncthreads per K-step.
// ---------------------------------------------------------------------------
#define BM 256
#define BN 256

__global__ __launch_bounds__(512, 2) void k_gemm(
    const ushort_t* __restrict__ hcP, const float* __restrict__ M0f,
    const float* __restrict__ M1f, const ushort_t* __restrict__ W2T,
    const float* __restrict__ epf, const float* __restrict__ b2f,
    const int* __restrict__ flag, void* __restrict__ outv) {
  __shared__ ushort_t bLds[2][BN * 64];  // 2 x 32 KB, XOR-chunk swizzled

  const int t = threadIdx.x;
  const int w = t >> 6;
  const int lane = t & 63;

  // XCD-aware decode (grid 256 = 8 XCDs x 32 blocks)
  const int xcd = blockIdx.x & 7;
  const int idx = blockIdx.x >> 3;
  const int nb = xcd >> 1;                // N quarter (256 cols)
  const int mb = ((xcd & 1) << 5) | idx;  // 0..63 M tile (256 rows)
  const int s = mb >> 2;                  // scene
  const int a0 = (mb & 3) << 3;           // first of 8 a-values
  const int isbf = *flag;

  const int wm = w >> 1;  // 0..3 : m-quarter (64 rows)
  const int wn = w & 1;   // 0..1 : n-half (128 cols)
  const int rl = lane & 15, q = lane >> 4;

  // ---- rr[g2][bi]: a = a0 + wm*2 + g2 ; b = bi*16 + rl (per-lane) ----
  float rr0[2][2], rr1[2][2];
#pragma unroll
  for (int g2 = 0; g2 < 2; ++g2) {
    int pa = s * NPED + a0 + wm * 2 + g2;
    float ax = epf[pa * 2], ay = epf[pa * 2 + 1];
#pragma unroll
    for (int bi = 0; bi < 2; ++bi) {
      int pb = s * NPED + rl + bi * 16;
      rr0[g2][bi] = clip1(epf[pb * 2] - ax);
      rr1[g2][bi] = clip1(epf[pb * 2 + 1] - ay);
    }
  }

  // ---- A-gen gather base: hcP[s] + lane row offset (COALESCED layout) ----
  const ushort_t* hcPs = hcP + (size_t)s * 1024 * 256 + rl * 8;  // + chunk*256 (+128 for bi=1)

  // ---- B DMA addressing (XOR chunk swizzle, slot = chunk ^ (row&7)) ----
  const int rowl = w * 8 + (lane >> 3);
  const int chl = (lane & 7) ^ ((lane >> 3) & 7);
  const ushort_t* bGlob = W2T + (size_t)(nb * BN + rowl) * D1 + chl * 8;
  ushort_t* bWr = &bLds[0][0] + rowl * 64 + (lane & 7) * 8;  // uniform + lane*16B

  // ---- B fragment read addressing ----
  const int bRd = (wn * 128 + rl) * 64;       // + nt*16*64 + slot*8
  const int swz0 = (q ^ (rl & 7)) * 8;        // ki=0: chunk q
  const int swz1 = ((q + 4) ^ (rl & 7)) * 8;  // ki=1: chunk q+4

  f32x4 acc[4][8];  // [m2][nt]
#pragma unroll
  for (int m2 = 0; m2 < 4; ++m2)
#pragma unroll
    for (int nt = 0; nt < 8; ++nt) acc[m2][nt] = (f32x4){0.f, 0.f, 0.f, 0.f};

#define STAGE(kt, buf)                                                      \
  do {                                                                      \
    const ushort_t* _s = bGlob + (kt) * 64;                                 \
    ushort_t* _d = bWr + (buf) * (BN * 64);                                 \
    async_load16(_s, _d);                                                   \
    async_load16(_s + (size_t)64 * D1, _d + 64 * 64);                       \
    async_load16(_s + (size_t)128 * D1, _d + 128 * 64);                     \
    async_load16(_s + (size_t)192 * D1, _d + 192 * 64);                     \
  } while (0)

  // ================= prologue =================
  STAGE(0, 0);
  __syncthreads();

  // ================= main loop: 128 K-steps =================
#pragma unroll 1
  for (int kt = 0; kt < 128; ++kt) {
    const int cur = kt & 1;
    STAGE((kt + 1) & 127, cur ^ 1);  // in flight across the whole step

    const ushort_t* bb = &bLds[0][0] + cur * (BN * 64);

#pragma unroll
    for (int ki = 0; ki < 2; ++ki) {
      // ---- gen operand loads (coalesced: lanes 0-15 contiguous 256B) ----
      const int chunk = kt * 8 + ki * 4 + q;
      const ushort_t* hp = hcPs + (size_t)chunk * 256;
      u32x4 hv0 = *(const u32x4*)(hp);        // b = rl
      u32x4 hv1 = *(const u32x4*)(hp + 128);  // b = rl + 16
      const int kk = kt * 64 + ki * 32 + q * 8;
      float4 m0a = *(const float4*)(M0f + kk);
      float4 m0b = *(const float4*)(M0f + kk + 4);
      float4 m1a = *(const float4*)(M1f + kk);
      float4 m1b = *(const float4*)(M1f + kk + 4);
      float h[2][8];
      unpk(hv0.x, h[0][0], h[0][1]); unpk(hv0.y, h[0][2], h[0][3]);
      unpk(hv0.z, h[0][4], h[0][5]); unpk(hv0.w, h[0][6], h[0][7]);
      unpk(hv1.x, h[1][0], h[1][1]); unpk(hv1.y, h[1][2], h[1][3]);
      unpk(hv1.z, h[1][4], h[1][5]); unpk(hv1.w, h[1][6], h[1][7]);
      // ---- generate A fragments in-register (frag m2: g2=m2>>1, bi=m2&1) ----
      bf16x8 af[4];
#pragma unroll
      for (int m2 = 0; m2 < 4; ++m2) {
        const int g2 = m2 >> 1, bi = m2 & 1;
        const float r0 = rr0[g2][bi], r1 = rr1[g2][bi];
        union { u32x4 u; bf16x8 b; } cv;
        cv.u.x = packbf(fmaxf(h[bi][0] + r0 * m0a.x + r1 * m1a.x, 0.f),
                        fmaxf(h[bi][1] + r0 * m0a.y + r1 * m1a.y, 0.f));
        cv.u.y = packbf(fmaxf(h[bi][2] + r0 * m0a.z + r1 * m1a.z, 0.f),
                        fmaxf(h[bi][3] + r0 * m0a.w + r1 * m1a.w, 0.f));
        cv.u.z = packbf(fmaxf(h[bi][4] + r0 * m0b.x + r1 * m1b.x, 0.f),
                        fmaxf(h[bi][5] + r0 * m0b.y + r1 * m1b.y, 0.f));
        cv.u.w = packbf(fmaxf(h[bi][6] + r0 * m0b.z + r1 * m1b.z, 0.f),
                        fmaxf(h[bi][7] + r0 * m0b.w + r1 * m1b.w, 0.f));
        af[m2] = cv.b;
      }
      // ---- B frags + MFMA (two n-halves of 4 frags to cap live regs) ----
      const int sw = ki ? swz1 : swz0;
#pragma unroll
      for (int nh = 0; nh < 2; ++nh) {
        bf16x8 bfr[4];
#pragma unroll
        for (int j = 0; j < 4; ++j)
          bfr[j] = *(const bf16x8*)(bb + bRd + (nh * 4 + j) * 16 * 64 + sw);
        __builtin_amdgcn_s_setprio(1);
#pragma unroll
        for (int m2 = 0; m2 < 4; ++m2)
#pragma unroll
          for (int j = 0; j < 4; ++j)
            acc[m2][nh * 4 + j] = __builtin_amdgcn_mfma_f32_16x16x32_bf16(
                af[m2], bfr[j], acc[m2][nh * 4 + j], 0, 0, 0);
        __builtin_amdgcn_s_setprio(0);
      }
    }
    __syncthreads();  // drains DMA (next B tile) + all LDS reads of cur
  }
#undef STAGE

  // ---- epilogue: max over b (32 per a), +b2, relu, store ----
  // acc[m2][nt] = C[wm*64 + m2*16 + q*4 + j][wn*128 + nt*16 + rl]
  // a_off = wm*2 + (m2>>1); b = (m2&1)*16 + q*4 + j.
#pragma unroll
  for (int g2 = 0; g2 < 2; ++g2) {
    int orow = s * NPED + a0 + wm * 2 + g2;
#pragma unroll
    for (int nt = 0; nt < 8; ++nt) {
      f32x4 x0 = acc[2 * g2][nt], x1 = acc[2 * g2 + 1][nt];
      float v = fmaxf(fmaxf(fmaxf(x0.x, x0.y), fmaxf(x0.z, x0.w)),
                      fmaxf(fmaxf(x1.x, x1.y), fmaxf(x1.z, x1.w)));
      v = fmaxf(v, __shfl_xor(v, 16, 64));
      v = fmaxf(v, __shfl_xor(v, 32, 64));
      if (lane < 16) {
        int col = nb * BN + wn * 128 + nt * 16 + lane;
        float o = fmaxf(v + b2f[col], 0.f);
        if (isbf)
          ((ushort_t*)outv)[(size_t)orow * BOTN + col] = f2bf(o);
        else
          ((float*)outv)[(size_t)orow * BOTN + col] = o;
      }
    }
  }
}

extern "C" void kernel_launch(void* const* d_in, const int* in_sizes, int n_in,
                              void* d_out, int out_size, void* d_ws, size_t ws_size,
                              hipStream_t stream) {
  (void)in_sizes; (void)n_in; (void)out_size; (void)ws_size;
  const void* h_states = d_in[0];
  const void* end_pos = d_in[1];
  // d_in[2] rel_pos: unused by reference; d_in[3] seq_start_end: fixed equal scenes
  const void* W_sp = d_in[4];
  const void* b_sp = d_in[5];
  const void* W1 = d_in[6];
  const void* b1 = d_in[7];
  const void* W2 = d_in[8];
  const void* b2 = d_in[9];

  char* ws = (char*)d_ws;
  ushort_t* hcP = (ushort_t*)ws;                         // 8 MB  (16x1024x32x8 bf16)
  ushort_t* W2T = (ushort_t*)(ws + (8u << 20));          // 16 MB (1024x8192 bf16)
  float* M0f = (float*)(ws + (24u << 20));               // 32 KB
  float* M1f = (float*)(ws + (24u << 20) + 32768);       // 32 KB
  float* epf = (float*)(ws + (24u << 20) + 98304);       // 4 KB
  float* b2f = (float*)(ws + (24u << 20) + 102400);      // 4 KB
  int* flag = (int*)(ws + (24u << 20) + 106496);         // 4 B

  k_pre<<<dim3(2337), dim3(256), 0, stream>>>(
      h_states, end_pos, W_sp, b_sp, W1, b1, W2, b2,
      flag, epf, b2f, M0f, M1f, hcP, W2T);
  k_gemm<<<dim3(256), dim3(512), 0, stream>>>(hcP, M0f, M1f, W2T, epf, b2f, flag, d_out);
}